// Round 2
// baseline (384.276 us; speedup 1.0000x reference)
//
#include <hip/hip_runtime.h>
#include <hip/hip_bf16.h>

#define D_MODEL 256
#define N_HEADS 8
#define D_HEAD 32
#define N_LEVELS 4
#define N_POINTS 4
#define LEN_IN 21760
#define N_BATCH 8
#define LEN_Q 1000

typedef __attribute__((ext_vector_type(8))) short short8;
typedef __attribute__((ext_vector_type(4))) float f32x4;

__device__ __forceinline__ unsigned short f2bf(float f) {
    unsigned int u = __float_as_uint(f);
    u += 0x7FFFu + ((u >> 16) & 1u);   // RNE
    return (unsigned short)(u >> 16);
}
__device__ __forceinline__ float bf2f(unsigned short s) {
    return __uint_as_float(((unsigned int)s) << 16);
}

// ---------------------------------------------------------------------------
// prep: transpose + bf16-convert the three weight matrices; concat biases.
//   WtV [256][256]  <- W_val^T
//   WtC [384][256]  <- [W_off | W_attn]^T
//   WtO [256][256]  <- W_out^T
//   bcat[384]       <- [b_off | b_attn]
// ---------------------------------------------------------------------------
__global__ __launch_bounds__(256) void prep_kernel(
    const float* __restrict__ Wv, const float* __restrict__ Wo,
    const float* __restrict__ Wa, const float* __restrict__ Wu,
    const float* __restrict__ boff, const float* __restrict__ battn,
    unsigned short* __restrict__ WtV, unsigned short* __restrict__ WtC,
    unsigned short* __restrict__ WtO, float* __restrict__ bcat)
{
    int idx = blockIdx.x * 256 + threadIdx.x;
    if (idx < 65536) {
        int n = idx >> 8, k = idx & 255;
        WtV[idx] = f2bf(Wv[k * 256 + n]);
    } else if (idx < 65536 + 98304) {
        int j = idx - 65536;
        int n = j >> 8, k = j & 255;
        float s = (n < 256) ? Wo[k * 256 + n] : Wa[k * 128 + (n - 256)];
        WtC[j] = f2bf(s);
    } else if (idx < 65536 + 98304 + 65536) {
        int j = idx - (65536 + 98304);
        int n = j >> 8, k = j & 255;
        WtO[j] = f2bf(Wu[k * 256 + n]);
    } else if (idx < 65536 + 98304 + 65536 + 384) {
        int j = idx - (65536 + 98304 + 65536);
        bcat[j] = (j < 256) ? boff[j] : battn[j - 256];
    }
}

// ---------------------------------------------------------------------------
// Generic K=256 MFMA GEMM:  C[M][N] = A_f32[M][256] @ Wt_bf16[N][256]^T + bias
// BM=32, 256 threads = 4 waves, wave w owns cols [w*NF*16, (w+1)*NF*16).
// N = NF*64.  No LDS: A fragments loaded fp32->bf16 in-register, B fragments
// 16B bf16 loads from the transposed weight (L1/L2-hot).
// mfma_f32_16x16x32_bf16 layouts:
//   A: row = lane&15,            k = 8*(lane>>4)+j
//   B: col = lane&15,            k = 8*(lane>>4)+j
//   D: col = lane&15, row = 4*(lane>>4)+r        (m89-verified)
// ---------------------------------------------------------------------------
template<int NF, bool OBF16>
__global__ __launch_bounds__(256) void gemm_k256(
    const float* __restrict__ A, const unsigned short* __restrict__ Wt,
    const float* __restrict__ bias, void* __restrict__ Cv)
{
    const int wave = threadIdx.x >> 6;
    const int lane = threadIdx.x & 63;
    const int lhi = lane >> 4, llo = lane & 15;
    const int mBase = blockIdx.x * 32;
    const int colBase = wave * (NF * 16);
    const int N = NF * 64;

    f32x4 acc[2][NF];
#pragma unroll
    for (int m = 0; m < 2; ++m)
#pragma unroll
        for (int n = 0; n < NF; ++n)
            acc[m][n] = (f32x4){0.f, 0.f, 0.f, 0.f};

#pragma unroll
    for (int ks = 0; ks < 8; ++ks) {
        const int kk = ks * 32 + lhi * 8;
        short8 a[2], b[NF];
#pragma unroll
        for (int m = 0; m < 2; ++m) {
            const float* ap = A + (size_t)(mBase + m * 16 + llo) * 256 + kk;
            f32x4 f0 = *reinterpret_cast<const f32x4*>(ap);
            f32x4 f1 = *reinterpret_cast<const f32x4*>(ap + 4);
            short8 t;
            t[0] = (short)f2bf(f0[0]); t[1] = (short)f2bf(f0[1]);
            t[2] = (short)f2bf(f0[2]); t[3] = (short)f2bf(f0[3]);
            t[4] = (short)f2bf(f1[0]); t[5] = (short)f2bf(f1[1]);
            t[6] = (short)f2bf(f1[2]); t[7] = (short)f2bf(f1[3]);
            a[m] = t;
        }
#pragma unroll
        for (int n = 0; n < NF; ++n) {
            const unsigned short* bp =
                Wt + (size_t)(colBase + n * 16 + llo) * 256 + kk;
            b[n] = *reinterpret_cast<const short8*>(bp);
        }
#pragma unroll
        for (int m = 0; m < 2; ++m)
#pragma unroll
            for (int n = 0; n < NF; ++n)
                acc[m][n] = __builtin_amdgcn_mfma_f32_16x16x32_bf16(
                    a[m], b[n], acc[m][n], 0, 0, 0);
    }

#pragma unroll
    for (int m = 0; m < 2; ++m) {
        const int row0 = mBase + m * 16 + lhi * 4;
#pragma unroll
        for (int n = 0; n < NF; ++n) {
            const int col = colBase + n * 16 + llo;
            const float bb = bias[col];
#pragma unroll
            for (int r = 0; r < 4; ++r) {
                float v = acc[m][n][r] + bb;
                size_t idx = (size_t)(row0 + r) * N + col;
                if (OBF16) ((unsigned short*)Cv)[idx] = f2bf(v);
                else       ((float*)Cv)[idx] = v;
            }
        }
    }
}

// ---------------------------------------------------------------------------
// Sampling: block = one (b,q), wave = one head (512 threads = 8 waves = 8
// heads). 32 lanes = D_HEAD dims; two 32-lane halves (g=0,1) split the 16
// (level,point) samples by parity. Level geometry is compile-time.
// ---------------------------------------------------------------------------
__global__ __launch_bounds__(512) void ms_sample_kernel(
    const unsigned short* __restrict__ value,  // [8*21760][256] bf16
    const float* __restrict__ proj,            // [8000][384] f32
    const float* __restrict__ refp,            // [8][1000][4][2] f32
    float* __restrict__ out_h)                 // [8000][256] f32
{
    const int bq = blockIdx.x;
    const int b = bq / LEN_Q;
    const int h = threadIdx.x >> 6;            // 0..7
    const int lane = threadIdx.x & 63;
    const int g = lane >> 5, d = lane & 31;

    const float* prow = proj + (size_t)bq * 384;

    // softmax over the 16 logits of this head
    float lg[16];
    float mx = -1e30f;
#pragma unroll
    for (int s = 0; s < 16; ++s) {
        lg[s] = prow[256 + h * 16 + s];
        mx = fmaxf(mx, lg[s]);
    }
    float den = 0.f;
    float myw[8];
#pragma unroll
    for (int s = 0; s < 16; ++s) {
        float e = __expf(lg[s] - mx);
        den += e;
        if ((s & 1) == g) myw[s >> 1] = e;   // static index, one hit per t
    }
    const float inv = 1.f / den;

    static const int STL[4] = {0, 16384, 20480, 21504};

    const unsigned short* vb0 = value + ((size_t)b * LEN_IN) * 256 + h * 32 + d;
    float acc = 0.f;
#pragma unroll
    for (int t = 0; t < 8; ++t) {
        const int l = t >> 1;                 // compile-time per unrolled t
        const int Wl = 128 >> l, Hl = 128 >> l;
        const int st = STL[l];                // constant-folded
        const int s = (t << 1) | g;

        const float dx = prow[h * 32 + (s << 1)];
        const float dy = prow[h * 32 + (s << 1) + 1];
        const float rx = refp[((size_t)bq * 4 + l) * 2 + 0];
        const float ry = refp[((size_t)bq * 4 + l) * 2 + 1];

        const float x = rx * (float)Wl + dx - 0.5f;
        const float y = ry * (float)Hl + dy - 0.5f;
        const float x0f = floorf(x), y0f = floorf(y);
        const int x0 = (int)x0f, y0 = (int)y0f;
        const float wx1 = x - x0f, wy1 = y - y0f;
        const float wx0 = 1.f - wx1, wy0 = 1.f - wy1;
        const float w = myw[t] * inv;

        const bool xv0 = (x0 >= 0) & (x0 < Wl);
        const bool xv1 = (x0 + 1 >= 0) & (x0 + 1 < Wl);
        const bool yv0 = (y0 >= 0) & (y0 < Hl);
        const bool yv1 = (y0 + 1 >= 0) & (y0 + 1 < Hl);

        float v00 = 0.f, v01 = 0.f, v10 = 0.f, v11 = 0.f;
        const unsigned short* vb = vb0 + (size_t)st * 256;
        if (yv0) {
            const unsigned short* r0 = vb + (size_t)y0 * Wl * 256;
            if (xv0) v00 = bf2f(r0[(size_t)x0 * 256]);
            if (xv1) v01 = bf2f(r0[(size_t)(x0 + 1) * 256]);
        }
        if (yv1) {
            const unsigned short* r1 = vb + (size_t)(y0 + 1) * Wl * 256;
            if (xv0) v10 = bf2f(r1[(size_t)x0 * 256]);
            if (xv1) v11 = bf2f(r1[(size_t)(x0 + 1) * 256]);
        }
        acc += w * (wy0 * (wx0 * v00 + wx1 * v01) +
                    wy1 * (wx0 * v10 + wx1 * v11));
    }

    acc += __shfl_xor(acc, 32, 64);
    if (g == 0) out_h[(size_t)bq * 256 + h * 32 + d] = acc;
}

// ---------------------------------------------------------------------------
extern "C" void kernel_launch(void* const* d_in, const int* in_sizes, int n_in,
                              void* d_out, int out_size, void* d_ws, size_t ws_size,
                              hipStream_t stream)
{
    const float* query  = (const float*)d_in[0];
    const float* refp   = (const float*)d_in[1];
    const float* inpf   = (const float*)d_in[2];
    const float* W_off  = (const float*)d_in[5];
    const float* b_off  = (const float*)d_in[6];
    const float* W_attn = (const float*)d_in[7];
    const float* b_attn = (const float*)d_in[8];
    const float* W_val  = (const float*)d_in[9];
    const float* b_val  = (const float*)d_in[10];
    const float* W_out  = (const float*)d_in[11];
    const float* b_out  = (const float*)d_in[12];

    char* ws = (char*)d_ws;
    unsigned short* value = (unsigned short*)(ws);                    // 89,128,960 B
    float*          proj  = (float*)(ws + 89128960);                  // 12,288,000 B
    float*          out_h = (float*)(ws + 89128960 + 12288000);       //  8,192,000 B
    unsigned short* WtV   = (unsigned short*)(ws + 109608960);        //    131,072 B
    unsigned short* WtC   = (unsigned short*)(ws + 109740032);        //    196,608 B
    unsigned short* WtO   = (unsigned short*)(ws + 109936640);        //    131,072 B
    float*          bcat  = (float*)(ws + 110067712);                 //      1,536 B

    prep_kernel<<<898, 256, 0, stream>>>(W_val, W_off, W_attn, W_out,
                                         b_off, b_attn, WtV, WtC, WtO, bcat);

    // value = input_flatten @ W_val + b_val   -> bf16 [174080][256]
    gemm_k256<4, true><<<(N_BATCH * LEN_IN) / 32, 256, 0, stream>>>(
        inpf, WtV, b_val, (void*)value);

    // proj = query @ [W_off|W_attn] + [b_off|b_attn] -> f32 [8000][384]
    gemm_k256<6, false><<<(N_BATCH * LEN_Q) / 32, 256, 0, stream>>>(
        query, WtC, bcat, (void*)proj);

    // bilinear sampling + softmax-weighted sum -> out_h [8000][256]
    ms_sample_kernel<<<N_BATCH * LEN_Q, 512, 0, stream>>>(
        value, proj, refp, out_h);

    // out = out_h @ W_out + b_out -> d_out f32 [8000][256]
    gemm_k256<4, false><<<(N_BATCH * LEN_Q) / 32, 256, 0, stream>>>(
        out_h, WtO, b_out, d_out);
}

// Round 3
// 270.347 us; speedup vs baseline: 1.4214x; 1.4214x over previous
//
#include <hip/hip_runtime.h>
#include <hip/hip_bf16.h>

#define D_MODEL 256
#define N_HEADS 8
#define D_HEAD 32
#define N_LEVELS 4
#define N_POINTS 4
#define LEN_IN 21760
#define N_BATCH 8
#define LEN_Q 1000

typedef __attribute__((ext_vector_type(8))) short short8;
typedef __attribute__((ext_vector_type(4))) float f32x4;

typedef const __attribute__((address_space(1))) void* gp1;
typedef __attribute__((address_space(3))) void* lp3;

__device__ __forceinline__ unsigned short f2bf(float f) {
    unsigned int u = __float_as_uint(f);
    u += 0x7FFFu + ((u >> 16) & 1u);   // RNE
    return (unsigned short)(u >> 16);
}
__device__ __forceinline__ float bf2f(unsigned short s) {
    return __uint_as_float(((unsigned int)s) << 16);
}

// ---------------------------------------------------------------------------
// prep:
//   WtVp [8][16][64][8] bf16  <- W_val^T packed MFMA-fragment-major:
//        elem(ks,nf,lane,j) = W_val[k= ks*32+(lane>>4)*8+j][col= nf*16+(lane&15)]
//   WtC  [384][256] bf16      <- [W_off | W_attn]^T row-major
//   WtO  [256][256] bf16      <- W_out^T row-major
//   bcat [384] f32            <- [b_off | b_attn]
// ---------------------------------------------------------------------------
__global__ __launch_bounds__(256) void prep_kernel(
    const float* __restrict__ Wv, const float* __restrict__ Wo,
    const float* __restrict__ Wa, const float* __restrict__ Wu,
    const float* __restrict__ boff, const float* __restrict__ battn,
    unsigned short* __restrict__ WtVp, unsigned short* __restrict__ WtC,
    unsigned short* __restrict__ WtO, float* __restrict__ bcat)
{
    int idx = blockIdx.x * 256 + threadIdx.x;
    if (idx < 65536) {
        int j = idx & 7, lane = (idx >> 3) & 63, nf = (idx >> 9) & 15, ks = idx >> 13;
        int col = nf * 16 + (lane & 15);
        int k = ks * 32 + (lane >> 4) * 8 + j;
        WtVp[idx] = f2bf(Wv[k * 256 + col]);
    } else if (idx < 65536 + 98304) {
        int j = idx - 65536;
        int n = j >> 8, k = j & 255;
        float s = (n < 256) ? Wo[k * 256 + n] : Wa[k * 128 + (n - 256)];
        WtC[j] = f2bf(s);
    } else if (idx < 65536 + 98304 + 65536) {
        int j = idx - (65536 + 98304);
        int n = j >> 8, k = j & 255;
        WtO[j] = f2bf(Wu[k * 256 + n]);
    } else if (idx < 65536 + 98304 + 65536 + 384) {
        int j = idx - (65536 + 98304 + 65536);
        bcat[j] = (j < 256) ? boff[j] : battn[j - 256];
    }
}

// ---------------------------------------------------------------------------
// Value GEMM: C_bf16[174080][256] = A_f32[174080][256] @ W_val + bias
// BM=64, BK=32, 256 thr = 4 waves; wave w owns cols [w*64, w*64+64).
// A staged global->LDS via global_load_lds dwordx4 (double-buffered 2x8KB),
// XOR-swizzle (byte ^= (row&7)<<4) applied on the SOURCE address (LDS dest
// linear, per m104/m173) and reapplied on ds_read_b128 -> conflict-free.
// B pre-packed fragment-major: 1KB coalesced load per (ks,nf), L2-hot.
// Schedule: loadB; stage(next); vmcnt(2); bar; ds_read+cvt; 16 MFMA; bar.
// ---------------------------------------------------------------------------
__global__ __launch_bounds__(256) void gemm_value(
    const float* __restrict__ A,
    const unsigned short* __restrict__ Bp,   // [8][16][64][8] bf16
    const float* __restrict__ bias,
    unsigned short* __restrict__ C)
{
    __shared__ float lds[2][2048];           // 2 x 8KB (BM=64 rows x 128B)

    const int tid = threadIdx.x;
    const int wave = tid >> 6, lane = tid & 63;
    const int lhi = lane >> 4, llo = lane & 15;
    const int mBase = blockIdx.x * 64;

    // staging geometry: thread stages 16B at linear tile offset tid*16 (call0)
    // and tid*16+4096 (call1). row = off/128 (rows 0..31 / 32..63), cb = off%128.
    const int soff = tid * 16;
    const int r0 = soff >> 7, cb0 = soff & 127;
    const size_t g0 = (size_t)r0 * 1024 + (size_t)(cb0 ^ ((r0 & 7) << 4));
    const size_t g1 = g0 + (size_t)32 * 1024;    // row+32 has same (row&7)

    const char* Ab = (const char*)(A + (size_t)mBase * 256);
    const int dsto = soff >> 2;                   // float index in tile

    f32x4 acc[4][4];
#pragma unroll
    for (int mf = 0; mf < 4; ++mf)
#pragma unroll
        for (int n = 0; n < 4; ++n)
            acc[mf][n] = (f32x4){0.f, 0.f, 0.f, 0.f};

    // prologue: stage k-tile 0 into buf 0
    {
        float* dst0 = &lds[0][dsto];
        __builtin_amdgcn_global_load_lds((gp1)(const void*)(Ab + g0),
                                         (lp3)dst0, 16, 0, 0);
        __builtin_amdgcn_global_load_lds((gp1)(const void*)(Ab + g1),
                                         (lp3)(dst0 + 1024), 16, 0, 0);
    }

#pragma unroll
    for (int kt = 0; kt < 8; ++kt) {
        const int cur = kt & 1;

        // B fragments for this k-step (coalesced 1KB each, L2-hot)
        short8 b[4];
#pragma unroll
        for (int n = 0; n < 4; ++n)
            b[n] = *reinterpret_cast<const short8*>(
                Bp + ((size_t)(kt * 16 + wave * 4 + n) * 64 + lane) * 8);

        // prefetch next k-tile into other buffer
        if (kt < 7) {
            const size_t off = (size_t)(kt + 1) * 128;
            float* dst0 = &lds[cur ^ 1][dsto];
            __builtin_amdgcn_global_load_lds((gp1)(const void*)(Ab + off + g0),
                                             (lp3)dst0, 16, 0, 0);
            __builtin_amdgcn_global_load_lds((gp1)(const void*)(Ab + off + g1),
                                             (lp3)(dst0 + 1024), 16, 0, 0);
        }

        __builtin_amdgcn_sched_barrier(0);
        if (kt < 7) asm volatile("s_waitcnt vmcnt(2)" ::: "memory");
        else        asm volatile("s_waitcnt vmcnt(0)" ::: "memory");
        __builtin_amdgcn_sched_barrier(0);
        __builtin_amdgcn_s_barrier();
        __builtin_amdgcn_sched_barrier(0);

        // A fragments from LDS (swizzled), f32 -> bf16 in-register
        short8 af[4];
#pragma unroll
        for (int mf = 0; mf < 4; ++mf) {
            const int row = mf * 16 + llo;
            const int sz = (llo & 7) << 4;
            const char* base = (const char*)&lds[cur][0] + row * 128;
            f32x4 flo = *reinterpret_cast<const f32x4*>(base + ((lhi * 32) ^ sz));
            f32x4 fhi = *reinterpret_cast<const f32x4*>(base + ((lhi * 32 + 16) ^ sz));
            short8 t;
            t[0] = (short)f2bf(flo[0]); t[1] = (short)f2bf(flo[1]);
            t[2] = (short)f2bf(flo[2]); t[3] = (short)f2bf(flo[3]);
            t[4] = (short)f2bf(fhi[0]); t[5] = (short)f2bf(fhi[1]);
            t[6] = (short)f2bf(fhi[2]); t[7] = (short)f2bf(fhi[3]);
            af[mf] = t;
        }

#pragma unroll
        for (int mf = 0; mf < 4; ++mf)
#pragma unroll
            for (int n = 0; n < 4; ++n)
                acc[mf][n] = __builtin_amdgcn_mfma_f32_16x16x32_bf16(
                    af[mf], b[n], acc[mf][n], 0, 0, 0);

        __builtin_amdgcn_sched_barrier(0);
        __builtin_amdgcn_s_barrier();
        __builtin_amdgcn_sched_barrier(0);
    }

    // epilogue: D layout col=lane&15, row=4*(lane>>4)+r
#pragma unroll
    for (int mf = 0; mf < 4; ++mf) {
        const int row0 = mBase + mf * 16 + lhi * 4;
#pragma unroll
        for (int n = 0; n < 4; ++n) {
            const int col = wave * 64 + n * 16 + llo;
            const float bb = bias[col];
#pragma unroll
            for (int r = 0; r < 4; ++r)
                C[(size_t)(row0 + r) * 256 + col] = f2bf(acc[mf][n][r] + bb);
        }
    }
}

// ---------------------------------------------------------------------------
// Generic K=256 MFMA GEMM (small M): C[M][N] = A_f32[M][256] @ Wt^T + bias
// ---------------------------------------------------------------------------
template<int NF, bool OBF16>
__global__ __launch_bounds__(256) void gemm_k256(
    const float* __restrict__ A, const unsigned short* __restrict__ Wt,
    const float* __restrict__ bias, void* __restrict__ Cv)
{
    const int wave = threadIdx.x >> 6;
    const int lane = threadIdx.x & 63;
    const int lhi = lane >> 4, llo = lane & 15;
    const int mBase = blockIdx.x * 32;
    const int colBase = wave * (NF * 16);
    const int N = NF * 64;

    f32x4 acc[2][NF];
#pragma unroll
    for (int m = 0; m < 2; ++m)
#pragma unroll
        for (int n = 0; n < NF; ++n)
            acc[m][n] = (f32x4){0.f, 0.f, 0.f, 0.f};

#pragma unroll
    for (int ks = 0; ks < 8; ++ks) {
        const int kk = ks * 32 + lhi * 8;
        short8 a[2], b[NF];
#pragma unroll
        for (int m = 0; m < 2; ++m) {
            const float* ap = A + (size_t)(mBase + m * 16 + llo) * 256 + kk;
            f32x4 f0 = *reinterpret_cast<const f32x4*>(ap);
            f32x4 f1 = *reinterpret_cast<const f32x4*>(ap + 4);
            short8 t;
            t[0] = (short)f2bf(f0[0]); t[1] = (short)f2bf(f0[1]);
            t[2] = (short)f2bf(f0[2]); t[3] = (short)f2bf(f0[3]);
            t[4] = (short)f2bf(f1[0]); t[5] = (short)f2bf(f1[1]);
            t[6] = (short)f2bf(f1[2]); t[7] = (short)f2bf(f1[3]);
            a[m] = t;
        }
#pragma unroll
        for (int n = 0; n < NF; ++n) {
            const unsigned short* bp =
                Wt + (size_t)(colBase + n * 16 + llo) * 256 + kk;
            b[n] = *reinterpret_cast<const short8*>(bp);
        }
#pragma unroll
        for (int m = 0; m < 2; ++m)
#pragma unroll
            for (int n = 0; n < NF; ++n)
                acc[m][n] = __builtin_amdgcn_mfma_f32_16x16x32_bf16(
                    a[m], b[n], acc[m][n], 0, 0, 0);
    }

#pragma unroll
    for (int m = 0; m < 2; ++m) {
        const int row0 = mBase + m * 16 + lhi * 4;
#pragma unroll
        for (int n = 0; n < NF; ++n) {
            const int col = colBase + n * 16 + llo;
            const float bb = bias[col];
#pragma unroll
            for (int r = 0; r < 4; ++r) {
                float v = acc[m][n][r] + bb;
                size_t idx = (size_t)(row0 + r) * N + col;
                if (OBF16) ((unsigned short*)Cv)[idx] = f2bf(v);
                else       ((float*)Cv)[idx] = v;
            }
        }
    }
}

// ---------------------------------------------------------------------------
// Sampling: block = one (b,q), wave = one head (512 threads = 8 waves).
// ---------------------------------------------------------------------------
__global__ __launch_bounds__(512) void ms_sample_kernel(
    const unsigned short* __restrict__ value,  // [8*21760][256] bf16
    const float* __restrict__ proj,            // [8000][384] f32
    const float* __restrict__ refp,            // [8][1000][4][2] f32
    float* __restrict__ out_h)                 // [8000][256] f32
{
    const int bq = blockIdx.x;
    const int b = bq / LEN_Q;
    const int h = threadIdx.x >> 6;            // 0..7
    const int lane = threadIdx.x & 63;
    const int g = lane >> 5, d = lane & 31;

    const float* prow = proj + (size_t)bq * 384;

    float lg[16];
    float mx = -1e30f;
#pragma unroll
    for (int s = 0; s < 16; ++s) {
        lg[s] = prow[256 + h * 16 + s];
        mx = fmaxf(mx, lg[s]);
    }
    float den = 0.f;
    float myw[8];
#pragma unroll
    for (int s = 0; s < 16; ++s) {
        float e = __expf(lg[s] - mx);
        den += e;
        if ((s & 1) == g) myw[s >> 1] = e;
    }
    const float inv = 1.f / den;

    static const int STL[4] = {0, 16384, 20480, 21504};

    const unsigned short* vb0 = value + ((size_t)b * LEN_IN) * 256 + h * 32 + d;
    float acc = 0.f;
#pragma unroll
    for (int t = 0; t < 8; ++t) {
        const int l = t >> 1;
        const int Wl = 128 >> l, Hl = 128 >> l;
        const int st = STL[l];
        const int s = (t << 1) | g;

        const float dx = prow[h * 32 + (s << 1)];
        const float dy = prow[h * 32 + (s << 1) + 1];
        const float rx = refp[((size_t)bq * 4 + l) * 2 + 0];
        const float ry = refp[((size_t)bq * 4 + l) * 2 + 1];

        const float x = rx * (float)Wl + dx - 0.5f;
        const float y = ry * (float)Hl + dy - 0.5f;
        const float x0f = floorf(x), y0f = floorf(y);
        const int x0 = (int)x0f, y0 = (int)y0f;
        const float wx1 = x - x0f, wy1 = y - y0f;
        const float wx0 = 1.f - wx1, wy0 = 1.f - wy1;
        const float w = myw[t] * inv;

        const bool xv0 = (x0 >= 0) & (x0 < Wl);
        const bool xv1 = (x0 + 1 >= 0) & (x0 + 1 < Wl);
        const bool yv0 = (y0 >= 0) & (y0 < Hl);
        const bool yv1 = (y0 + 1 >= 0) & (y0 + 1 < Hl);

        float v00 = 0.f, v01 = 0.f, v10 = 0.f, v11 = 0.f;
        const unsigned short* vb = vb0 + (size_t)st * 256;
        if (yv0) {
            const unsigned short* r0 = vb + (size_t)y0 * Wl * 256;
            if (xv0) v00 = bf2f(r0[(size_t)x0 * 256]);
            if (xv1) v01 = bf2f(r0[(size_t)(x0 + 1) * 256]);
        }
        if (yv1) {
            const unsigned short* r1 = vb + (size_t)(y0 + 1) * Wl * 256;
            if (xv0) v10 = bf2f(r1[(size_t)x0 * 256]);
            if (xv1) v11 = bf2f(r1[(size_t)(x0 + 1) * 256]);
        }
        acc += w * (wy0 * (wx0 * v00 + wx1 * v01) +
                    wy1 * (wx0 * v10 + wx1 * v11));
    }

    acc += __shfl_xor(acc, 32, 64);
    if (g == 0) out_h[(size_t)bq * 256 + h * 32 + d] = acc;
}

// ---------------------------------------------------------------------------
extern "C" void kernel_launch(void* const* d_in, const int* in_sizes, int n_in,
                              void* d_out, int out_size, void* d_ws, size_t ws_size,
                              hipStream_t stream)
{
    const float* query  = (const float*)d_in[0];
    const float* refp   = (const float*)d_in[1];
    const float* inpf   = (const float*)d_in[2];
    const float* W_off  = (const float*)d_in[5];
    const float* b_off  = (const float*)d_in[6];
    const float* W_attn = (const float*)d_in[7];
    const float* b_attn = (const float*)d_in[8];
    const float* W_val  = (const float*)d_in[9];
    const float* b_val  = (const float*)d_in[10];
    const float* W_out  = (const float*)d_in[11];
    const float* b_out  = (const float*)d_in[12];

    char* ws = (char*)d_ws;
    unsigned short* value = (unsigned short*)(ws);                    // 89,128,960 B
    float*          proj  = (float*)(ws + 89128960);                  // 12,288,000 B
    float*          out_h = (float*)(ws + 89128960 + 12288000);       //  8,192,000 B
    unsigned short* WtVp  = (unsigned short*)(ws + 109608960);        //    131,072 B
    unsigned short* WtC   = (unsigned short*)(ws + 109740032);        //    196,608 B
    unsigned short* WtO   = (unsigned short*)(ws + 109936640);        //    131,072 B
    float*          bcat  = (float*)(ws + 110067712);                 //      1,536 B

    prep_kernel<<<898, 256, 0, stream>>>(W_val, W_off, W_attn, W_out,
                                         b_off, b_attn, WtVp, WtC, WtO, bcat);

    // value = input_flatten @ W_val + b_val   -> bf16 [174080][256]
    gemm_value<<<(N_BATCH * LEN_IN) / 64, 256, 0, stream>>>(
        inpf, WtVp, b_val, value);

    // proj = query @ [W_off|W_attn] + bias -> f32 [8000][384]
    gemm_k256<6, false><<<(N_BATCH * LEN_Q) / 32, 256, 0, stream>>>(
        query, WtC, bcat, (void*)proj);

    // bilinear sampling + softmax-weighted sum -> out_h [8000][256]
    ms_sample_kernel<<<N_BATCH * LEN_Q, 512, 0, stream>>>(
        value, proj, refp, out_h);

    // out = out_h @ W_out + b_out -> d_out f32 [8000][256]
    gemm_k256<4, false><<<(N_BATCH * LEN_Q) / 32, 256, 0, stream>>>(
        out_h, WtO, b_out, d_out);
}

// Round 4
// 141.030 us; speedup vs baseline: 2.7248x; 1.9170x over previous
//
#include <hip/hip_runtime.h>
#include <hip/hip_bf16.h>

#define D_MODEL 256
#define N_HEADS 8
#define D_HEAD 32
#define N_LEVELS 4
#define N_POINTS 4
#define LEN_IN 21760
#define N_BATCH 8
#define LEN_Q 1000

typedef __attribute__((ext_vector_type(8))) short short8;
typedef __attribute__((ext_vector_type(4))) float f32x4;

typedef const __attribute__((address_space(1))) void* gp1;
typedef __attribute__((address_space(3))) void* lp3;

__device__ __forceinline__ unsigned short f2bf(float f) {
    unsigned int u = __float_as_uint(f);
    u += 0x7FFFu + ((u >> 16) & 1u);   // RNE
    return (unsigned short)(u >> 16);
}
__device__ __forceinline__ float bf2f(unsigned short s) {
    return __uint_as_float(((unsigned int)s) << 16);
}

// ---------------------------------------------------------------------------
// prep:
//   WtVp [8][16][64][8] bf16  <- W_val^T packed MFMA-fragment-major:
//        elem(ks,nf,lane,j) = W_val[k= ks*32+(lane>>4)*8+j][col= nf*16+(lane&15)]
//   WtC  [384][256] bf16      <- [W_off | W_attn]^T row-major
//   WtO  [256][256] bf16      <- W_out^T row-major
//   bcat [384] f32            <- [b_off | b_attn]
// ---------------------------------------------------------------------------
__global__ __launch_bounds__(256) void prep_kernel(
    const float* __restrict__ Wv, const float* __restrict__ Wo,
    const float* __restrict__ Wa, const float* __restrict__ Wu,
    const float* __restrict__ boff, const float* __restrict__ battn,
    unsigned short* __restrict__ WtVp, unsigned short* __restrict__ WtC,
    unsigned short* __restrict__ WtO, float* __restrict__ bcat)
{
    int idx = blockIdx.x * 256 + threadIdx.x;
    if (idx < 65536) {
        int j = idx & 7, lane = (idx >> 3) & 63, nf = (idx >> 9) & 15, ks = idx >> 13;
        int col = nf * 16 + (lane & 15);
        int k = ks * 32 + (lane >> 4) * 8 + j;
        WtVp[idx] = f2bf(Wv[k * 256 + col]);
    } else if (idx < 65536 + 98304) {
        int j = idx - 65536;
        int n = j >> 8, k = j & 255;
        float s = (n < 256) ? Wo[k * 256 + n] : Wa[k * 128 + (n - 256)];
        WtC[j] = f2bf(s);
    } else if (idx < 65536 + 98304 + 65536) {
        int j = idx - (65536 + 98304);
        int n = j >> 8, k = j & 255;
        WtO[j] = f2bf(Wu[k * 256 + n]);
    } else if (idx < 65536 + 98304 + 65536 + 384) {
        int j = idx - (65536 + 98304 + 65536);
        bcat[j] = (j < 256) ? boff[j] : battn[j - 256];
    }
}

// ---------------------------------------------------------------------------
// Value GEMM: C_bf16[174080][256] = A_f32[174080][256] @ W_val + bias
// (unchanged from round 3 — ~45us, near its 42us memory roofline)
// ---------------------------------------------------------------------------
__global__ __launch_bounds__(256) void gemm_value(
    const float* __restrict__ A,
    const unsigned short* __restrict__ Bp,   // [8][16][64][8] bf16
    const float* __restrict__ bias,
    unsigned short* __restrict__ C)
{
    __shared__ float lds[2][2048];           // 2 x 8KB (BM=64 rows x 128B)

    const int tid = threadIdx.x;
    const int wave = tid >> 6, lane = tid & 63;
    const int lhi = lane >> 4, llo = lane & 15;
    const int mBase = blockIdx.x * 64;

    const int soff = tid * 16;
    const int r0 = soff >> 7, cb0 = soff & 127;
    const size_t g0 = (size_t)r0 * 1024 + (size_t)(cb0 ^ ((r0 & 7) << 4));
    const size_t g1 = g0 + (size_t)32 * 1024;

    const char* Ab = (const char*)(A + (size_t)mBase * 256);
    const int dsto = soff >> 2;

    f32x4 acc[4][4];
#pragma unroll
    for (int mf = 0; mf < 4; ++mf)
#pragma unroll
        for (int n = 0; n < 4; ++n)
            acc[mf][n] = (f32x4){0.f, 0.f, 0.f, 0.f};

    {
        float* dst0 = &lds[0][dsto];
        __builtin_amdgcn_global_load_lds((gp1)(const void*)(Ab + g0),
                                         (lp3)dst0, 16, 0, 0);
        __builtin_amdgcn_global_load_lds((gp1)(const void*)(Ab + g1),
                                         (lp3)(dst0 + 1024), 16, 0, 0);
    }

#pragma unroll
    for (int kt = 0; kt < 8; ++kt) {
        const int cur = kt & 1;

        short8 b[4];
#pragma unroll
        for (int n = 0; n < 4; ++n)
            b[n] = *reinterpret_cast<const short8*>(
                Bp + ((size_t)(kt * 16 + wave * 4 + n) * 64 + lane) * 8);

        if (kt < 7) {
            const size_t off = (size_t)(kt + 1) * 128;
            float* dst0 = &lds[cur ^ 1][dsto];
            __builtin_amdgcn_global_load_lds((gp1)(const void*)(Ab + off + g0),
                                             (lp3)dst0, 16, 0, 0);
            __builtin_amdgcn_global_load_lds((gp1)(const void*)(Ab + off + g1),
                                             (lp3)(dst0 + 1024), 16, 0, 0);
        }

        __builtin_amdgcn_sched_barrier(0);
        if (kt < 7) asm volatile("s_waitcnt vmcnt(2)" ::: "memory");
        else        asm volatile("s_waitcnt vmcnt(0)" ::: "memory");
        __builtin_amdgcn_sched_barrier(0);
        __builtin_amdgcn_s_barrier();
        __builtin_amdgcn_sched_barrier(0);

        short8 af[4];
#pragma unroll
        for (int mf = 0; mf < 4; ++mf) {
            const int row = mf * 16 + llo;
            const int sz = (llo & 7) << 4;
            const char* base = (const char*)&lds[cur][0] + row * 128;
            f32x4 flo = *reinterpret_cast<const f32x4*>(base + ((lhi * 32) ^ sz));
            f32x4 fhi = *reinterpret_cast<const f32x4*>(base + ((lhi * 32 + 16) ^ sz));
            short8 t;
            t[0] = (short)f2bf(flo[0]); t[1] = (short)f2bf(flo[1]);
            t[2] = (short)f2bf(flo[2]); t[3] = (short)f2bf(flo[3]);
            t[4] = (short)f2bf(fhi[0]); t[5] = (short)f2bf(fhi[1]);
            t[6] = (short)f2bf(fhi[2]); t[7] = (short)f2bf(fhi[3]);
            af[mf] = t;
        }

#pragma unroll
        for (int mf = 0; mf < 4; ++mf)
#pragma unroll
            for (int n = 0; n < 4; ++n)
                acc[mf][n] = __builtin_amdgcn_mfma_f32_16x16x32_bf16(
                    af[mf], b[n], acc[mf][n], 0, 0, 0);

        __builtin_amdgcn_sched_barrier(0);
        __builtin_amdgcn_s_barrier();
        __builtin_amdgcn_sched_barrier(0);
    }

#pragma unroll
    for (int mf = 0; mf < 4; ++mf) {
        const int row0 = mBase + mf * 16 + lhi * 4;
#pragma unroll
        for (int n = 0; n < 4; ++n) {
            const int col = wave * 64 + n * 16 + llo;
            const float bb = bias[col];
#pragma unroll
            for (int r = 0; r < 4; ++r)
                C[(size_t)(row0 + r) * 256 + col] = f2bf(acc[mf][n][r] + bb);
        }
    }
}

// ---------------------------------------------------------------------------
// Generic K=256 MFMA GEMM (small M): C[M][N] = A_f32[M][256] @ Wt^T + bias
// ---------------------------------------------------------------------------
template<int NF, bool OBF16>
__global__ __launch_bounds__(256) void gemm_k256(
    const float* __restrict__ A, const unsigned short* __restrict__ Wt,
    const float* __restrict__ bias, void* __restrict__ Cv)
{
    const int wave = threadIdx.x >> 6;
    const int lane = threadIdx.x & 63;
    const int lhi = lane >> 4, llo = lane & 15;
    const int mBase = blockIdx.x * 32;
    const int colBase = wave * (NF * 16);
    const int N = NF * 64;

    f32x4 acc[2][NF];
#pragma unroll
    for (int m = 0; m < 2; ++m)
#pragma unroll
        for (int n = 0; n < NF; ++n)
            acc[m][n] = (f32x4){0.f, 0.f, 0.f, 0.f};

#pragma unroll
    for (int ks = 0; ks < 8; ++ks) {
        const int kk = ks * 32 + lhi * 8;
        short8 a[2], b[NF];
#pragma unroll
        for (int m = 0; m < 2; ++m) {
            const float* ap = A + (size_t)(mBase + m * 16 + llo) * 256 + kk;
            f32x4 f0 = *reinterpret_cast<const f32x4*>(ap);
            f32x4 f1 = *reinterpret_cast<const f32x4*>(ap + 4);
            short8 t;
            t[0] = (short)f2bf(f0[0]); t[1] = (short)f2bf(f0[1]);
            t[2] = (short)f2bf(f0[2]); t[3] = (short)f2bf(f0[3]);
            t[4] = (short)f2bf(f1[0]); t[5] = (short)f2bf(f1[1]);
            t[6] = (short)f2bf(f1[2]); t[7] = (short)f2bf(f1[3]);
            a[m] = t;
        }
#pragma unroll
        for (int n = 0; n < NF; ++n) {
            const unsigned short* bp =
                Wt + (size_t)(colBase + n * 16 + llo) * 256 + kk;
            b[n] = *reinterpret_cast<const short8*>(bp);
        }
#pragma unroll
        for (int m = 0; m < 2; ++m)
#pragma unroll
            for (int n = 0; n < NF; ++n)
                acc[m][n] = __builtin_amdgcn_mfma_f32_16x16x32_bf16(
                    a[m], b[n], acc[m][n], 0, 0, 0);
    }

#pragma unroll
    for (int m = 0; m < 2; ++m) {
        const int row0 = mBase + m * 16 + lhi * 4;
#pragma unroll
        for (int n = 0; n < NF; ++n) {
            const int col = colBase + n * 16 + llo;
            const float bb = bias[col];
#pragma unroll
            for (int r = 0; r < 4; ++r) {
                float v = acc[m][n][r] + bb;
                size_t idx = (size_t)(row0 + r) * N + col;
                if (OBF16) ((unsigned short*)Cv)[idx] = f2bf(v);
                else       ((float*)Cv)[idx] = v;
            }
        }
    }
}

// ---------------------------------------------------------------------------
// Sampling v2: block = one (b,q) [XCD-swizzled: b = blockIdx&7 so each
// batch's 11MB value slice stays on one XCD's L2], wave = one head.
// Wave = 4 groups x 16 lanes; group g handles point p=g of each level;
// lane ld=lane&15 covers dims {2ld, 2ld+1} via ushort2 loads.
// All 16 gathers (4 levels x 4 neighbors) issued branchlessly (clamp +
// zero-weight), then a separate accumulate phase -> 16 outstanding loads.
// ---------------------------------------------------------------------------
__global__ __launch_bounds__(512) void ms_sample_kernel(
    const unsigned short* __restrict__ value,  // [8*21760][256] bf16
    const float* __restrict__ proj,            // [8000][384] f32
    const float* __restrict__ refp,            // [8][1000][4][2] f32
    float* __restrict__ out_h)                 // [8000][256] f32
{
    const int bid = blockIdx.x;
    const int b = bid & 7;                     // XCD-pinned batch
    const int q = bid >> 3;
    const int bq = b * LEN_Q + q;

    const int h = threadIdx.x >> 6;            // 0..7
    const int lane = threadIdx.x & 63;
    const int g = lane >> 4;                   // point index p
    const int ld = lane & 15;                  // dim pair: dims 2ld, 2ld+1

    const float* prow = proj + (size_t)bq * 384;

    // softmax over this head's 16 logits (redundant per lane, L1-hot)
    float lg[16];
    float mx = -1e30f;
#pragma unroll
    for (int s = 0; s < 16; ++s) {
        lg[s] = prow[256 + h * 16 + s];
        mx = fmaxf(mx, lg[s]);
    }
    float den = 0.f;
    float myw[4];
#pragma unroll
    for (int s = 0; s < 16; ++s) {
        float e = __expf(lg[s] - mx);
        den += e;
        if ((s & 3) == g) myw[s >> 2] = e;     // static index per unrolled s
    }
    const float inv = 1.f / den;

    const unsigned short* vbase =
        value + (size_t)b * LEN_IN * 256 + h * 32 + 2 * ld;

    unsigned int vraw[4][4];
    float wgt[4][4];

    // phase 1: addresses + weights + all 16 loads (branchless)
#pragma unroll
    for (int l = 0; l < 4; ++l) {
        const int Wl = 128 >> l;               // Hl == Wl
        const int STL[4] = {0, 16384, 20480, 21504};
        const int st = STL[l];
        const int s = l * 4 + g;

        const float dx = prow[h * 32 + 2 * s];
        const float dy = prow[h * 32 + 2 * s + 1];
        const float rx = refp[((size_t)bq * 4 + l) * 2 + 0];
        const float ry = refp[((size_t)bq * 4 + l) * 2 + 1];

        const float x = rx * (float)Wl + dx - 0.5f;
        const float y = ry * (float)Wl + dy - 0.5f;
        const float x0f = floorf(x), y0f = floorf(y);
        const int x0 = (int)x0f, y0 = (int)y0f;
        const float wx1 = x - x0f, wy1 = y - y0f;
        const float wx0 = 1.f - wx1, wy0 = 1.f - wy1;
        const float ws = myw[l] * inv;

        const int x0c = min(max(x0, 0), Wl - 1);
        const int x1c = min(max(x0 + 1, 0), Wl - 1);
        const int y0c = min(max(y0, 0), Wl - 1);
        const int y1c = min(max(y0 + 1, 0), Wl - 1);
        const float fx0 = (x0 >= 0 && x0 < Wl) ? 1.f : 0.f;
        const float fx1 = (x0 + 1 >= 0 && x0 + 1 < Wl) ? 1.f : 0.f;
        const float fy0 = (y0 >= 0 && y0 < Wl) ? 1.f : 0.f;
        const float fy1 = (y0 + 1 >= 0 && y0 + 1 < Wl) ? 1.f : 0.f;

        const int r0 = st + y0c * Wl, r1 = st + y1c * Wl;
        vraw[l][0] = *reinterpret_cast<const unsigned int*>(vbase + (size_t)(r0 + x0c) * 256);
        vraw[l][1] = *reinterpret_cast<const unsigned int*>(vbase + (size_t)(r0 + x1c) * 256);
        vraw[l][2] = *reinterpret_cast<const unsigned int*>(vbase + (size_t)(r1 + x0c) * 256);
        vraw[l][3] = *reinterpret_cast<const unsigned int*>(vbase + (size_t)(r1 + x1c) * 256);
        wgt[l][0] = ws * wy0 * wx0 * fy0 * fx0;
        wgt[l][1] = ws * wy0 * wx1 * fy0 * fx1;
        wgt[l][2] = ws * wy1 * wx0 * fy1 * fx0;
        wgt[l][3] = ws * wy1 * wx1 * fy1 * fx1;
    }

    // phase 2: weighted accumulate (bf16 lo/hi -> f32)
    float ax = 0.f, ay = 0.f;
#pragma unroll
    for (int l = 0; l < 4; ++l)
#pragma unroll
        for (int n = 0; n < 4; ++n) {
            const unsigned int v = vraw[l][n];
            const float w = wgt[l][n];
            ax += w * bf2f((unsigned short)(v & 0xFFFFu));
            ay += w * bf2f((unsigned short)(v >> 16));
        }

    // reduce across the 4 groups (lanes ^16, ^32)
    ax += __shfl_xor(ax, 16, 64);
    ay += __shfl_xor(ay, 16, 64);
    ax += __shfl_xor(ax, 32, 64);
    ay += __shfl_xor(ay, 32, 64);

    if (g == 0) {
        float2 o = {ax, ay};
        *reinterpret_cast<float2*>(
            out_h + (size_t)bq * 256 + h * 32 + 2 * ld) = o;
    }
}

// ---------------------------------------------------------------------------
extern "C" void kernel_launch(void* const* d_in, const int* in_sizes, int n_in,
                              void* d_out, int out_size, void* d_ws, size_t ws_size,
                              hipStream_t stream)
{
    const float* query  = (const float*)d_in[0];
    const float* refp   = (const float*)d_in[1];
    const float* inpf   = (const float*)d_in[2];
    const float* W_off  = (const float*)d_in[5];
    const float* b_off  = (const float*)d_in[6];
    const float* W_attn = (const float*)d_in[7];
    const float* b_attn = (const float*)d_in[8];
    const float* W_val  = (const float*)d_in[9];
    const float* b_val  = (const float*)d_in[10];
    const float* W_out  = (const float*)d_in[11];
    const float* b_out  = (const float*)d_in[12];

    char* ws = (char*)d_ws;
    unsigned short* value = (unsigned short*)(ws);                    // 89,128,960 B
    float*          proj  = (float*)(ws + 89128960);                  // 12,288,000 B
    float*          out_h = (float*)(ws + 89128960 + 12288000);       //  8,192,000 B
    unsigned short* WtVp  = (unsigned short*)(ws + 109608960);        //    131,072 B
    unsigned short* WtC   = (unsigned short*)(ws + 109740032);        //    196,608 B
    unsigned short* WtO   = (unsigned short*)(ws + 109936640);        //    131,072 B
    float*          bcat  = (float*)(ws + 110067712);                 //      1,536 B

    prep_kernel<<<898, 256, 0, stream>>>(W_val, W_off, W_attn, W_out,
                                         b_off, b_attn, WtVp, WtC, WtO, bcat);

    // value = input_flatten @ W_val + b_val   -> bf16 [174080][256]
    gemm_value<<<(N_BATCH * LEN_IN) / 64, 256, 0, stream>>>(
        inpf, WtVp, b_val, value);

    // proj = query @ [W_off|W_attn] + bias -> f32 [8000][384]
    gemm_k256<6, false><<<(N_BATCH * LEN_Q) / 32, 256, 0, stream>>>(
        query, WtC, bcat, (void*)proj);

    // bilinear sampling + softmax-weighted sum -> out_h [8000][256]
    ms_sample_kernel<<<N_BATCH * LEN_Q, 512, 0, stream>>>(
        value, proj, refp, out_h);

    // out = out_h @ W_out + b_out -> d_out f32 [8000][256]
    gemm_k256<4, false><<<(N_BATCH * LEN_Q) / 32, 256, 0, stream>>>(
        out_h, WtO, b_out, d_out);
}

// Round 5
// 136.822 us; speedup vs baseline: 2.8086x; 1.0308x over previous
//
#include <hip/hip_runtime.h>
#include <hip/hip_bf16.h>

#define D_MODEL 256
#define N_HEADS 8
#define D_HEAD 32
#define N_LEVELS 4
#define N_POINTS 4
#define LEN_IN 21760
#define N_BATCH 8
#define LEN_Q 1000

typedef __attribute__((ext_vector_type(8))) short short8;
typedef __attribute__((ext_vector_type(4))) float f32x4;

typedef const __attribute__((address_space(1))) void* gp1;
typedef __attribute__((address_space(3))) void* lp3;

__device__ __forceinline__ unsigned short f2bf(float f) {
    unsigned int u = __float_as_uint(f);
    u += 0x7FFFu + ((u >> 16) & 1u);   // RNE
    return (unsigned short)(u >> 16);
}
__device__ __forceinline__ float bf2f(unsigned short s) {
    return __uint_as_float(((unsigned int)s) << 16);
}

// ---------------------------------------------------------------------------
// prep:
//   WtVp [8][16][64][8] bf16  <- W_val^T packed MFMA-fragment-major
//   WtC  [384][256] bf16      <- [W_off | W_attn]^T row-major
//   WtO  [256][256] bf16      <- W_out^T row-major
//   bcat [384] f32            <- [b_off | b_attn]
// ---------------------------------------------------------------------------
__global__ __launch_bounds__(256) void prep_kernel(
    const float* __restrict__ Wv, const float* __restrict__ Wo,
    const float* __restrict__ Wa, const float* __restrict__ Wu,
    const float* __restrict__ boff, const float* __restrict__ battn,
    unsigned short* __restrict__ WtVp, unsigned short* __restrict__ WtC,
    unsigned short* __restrict__ WtO, float* __restrict__ bcat)
{
    int idx = blockIdx.x * 256 + threadIdx.x;
    if (idx < 65536) {
        int j = idx & 7, lane = (idx >> 3) & 63, nf = (idx >> 9) & 15, ks = idx >> 13;
        int col = nf * 16 + (lane & 15);
        int k = ks * 32 + (lane >> 4) * 8 + j;
        WtVp[idx] = f2bf(Wv[k * 256 + col]);
    } else if (idx < 65536 + 98304) {
        int j = idx - 65536;
        int n = j >> 8, k = j & 255;
        float s = (n < 256) ? Wo[k * 256 + n] : Wa[k * 128 + (n - 256)];
        WtC[j] = f2bf(s);
    } else if (idx < 65536 + 98304 + 65536) {
        int j = idx - (65536 + 98304);
        int n = j >> 8, k = j & 255;
        WtO[j] = f2bf(Wu[k * 256 + n]);
    } else if (idx < 65536 + 98304 + 65536 + 384) {
        int j = idx - (65536 + 98304 + 65536);
        bcat[j] = (j < 256) ? boff[j] : battn[j - 256];
    }
}

// ---------------------------------------------------------------------------
// Value GEMM: C_bf16[174080][256] = A_f32[174080][256] @ W_val + bias
// (unchanged — ~50us vs 42us memory roofline)
// ---------------------------------------------------------------------------
__global__ __launch_bounds__(256) void gemm_value(
    const float* __restrict__ A,
    const unsigned short* __restrict__ Bp,   // [8][16][64][8] bf16
    const float* __restrict__ bias,
    unsigned short* __restrict__ C)
{
    __shared__ float lds[2][2048];           // 2 x 8KB (BM=64 rows x 128B)

    const int tid = threadIdx.x;
    const int wave = tid >> 6, lane = tid & 63;
    const int lhi = lane >> 4, llo = lane & 15;
    const int mBase = blockIdx.x * 64;

    const int soff = tid * 16;
    const int r0 = soff >> 7, cb0 = soff & 127;
    const size_t g0 = (size_t)r0 * 1024 + (size_t)(cb0 ^ ((r0 & 7) << 4));
    const size_t g1 = g0 + (size_t)32 * 1024;

    const char* Ab = (const char*)(A + (size_t)mBase * 256);
    const int dsto = soff >> 2;

    f32x4 acc[4][4];
#pragma unroll
    for (int mf = 0; mf < 4; ++mf)
#pragma unroll
        for (int n = 0; n < 4; ++n)
            acc[mf][n] = (f32x4){0.f, 0.f, 0.f, 0.f};

    {
        float* dst0 = &lds[0][dsto];
        __builtin_amdgcn_global_load_lds((gp1)(const void*)(Ab + g0),
                                         (lp3)dst0, 16, 0, 0);
        __builtin_amdgcn_global_load_lds((gp1)(const void*)(Ab + g1),
                                         (lp3)(dst0 + 1024), 16, 0, 0);
    }

#pragma unroll
    for (int kt = 0; kt < 8; ++kt) {
        const int cur = kt & 1;

        short8 b[4];
#pragma unroll
        for (int n = 0; n < 4; ++n)
            b[n] = *reinterpret_cast<const short8*>(
                Bp + ((size_t)(kt * 16 + wave * 4 + n) * 64 + lane) * 8);

        if (kt < 7) {
            const size_t off = (size_t)(kt + 1) * 128;
            float* dst0 = &lds[cur ^ 1][dsto];
            __builtin_amdgcn_global_load_lds((gp1)(const void*)(Ab + off + g0),
                                             (lp3)dst0, 16, 0, 0);
            __builtin_amdgcn_global_load_lds((gp1)(const void*)(Ab + off + g1),
                                             (lp3)(dst0 + 1024), 16, 0, 0);
        }

        __builtin_amdgcn_sched_barrier(0);
        if (kt < 7) asm volatile("s_waitcnt vmcnt(2)" ::: "memory");
        else        asm volatile("s_waitcnt vmcnt(0)" ::: "memory");
        __builtin_amdgcn_sched_barrier(0);
        __builtin_amdgcn_s_barrier();
        __builtin_amdgcn_sched_barrier(0);

        short8 af[4];
#pragma unroll
        for (int mf = 0; mf < 4; ++mf) {
            const int row = mf * 16 + llo;
            const int sz = (llo & 7) << 4;
            const char* base = (const char*)&lds[cur][0] + row * 128;
            f32x4 flo = *reinterpret_cast<const f32x4*>(base + ((lhi * 32) ^ sz));
            f32x4 fhi = *reinterpret_cast<const f32x4*>(base + ((lhi * 32 + 16) ^ sz));
            short8 t;
            t[0] = (short)f2bf(flo[0]); t[1] = (short)f2bf(flo[1]);
            t[2] = (short)f2bf(flo[2]); t[3] = (short)f2bf(flo[3]);
            t[4] = (short)f2bf(fhi[0]); t[5] = (short)f2bf(fhi[1]);
            t[6] = (short)f2bf(fhi[2]); t[7] = (short)f2bf(fhi[3]);
            af[mf] = t;
        }

#pragma unroll
        for (int mf = 0; mf < 4; ++mf)
#pragma unroll
            for (int n = 0; n < 4; ++n)
                acc[mf][n] = __builtin_amdgcn_mfma_f32_16x16x32_bf16(
                    af[mf], b[n], acc[mf][n], 0, 0, 0);

        __builtin_amdgcn_sched_barrier(0);
        __builtin_amdgcn_s_barrier();
        __builtin_amdgcn_sched_barrier(0);
    }

#pragma unroll
    for (int mf = 0; mf < 4; ++mf) {
        const int row0 = mBase + mf * 16 + lhi * 4;
#pragma unroll
        for (int n = 0; n < 4; ++n) {
            const int col = wave * 64 + n * 16 + llo;
            const float bb = bias[col];
#pragma unroll
            for (int r = 0; r < 4; ++r)
                C[(size_t)(row0 + r) * 256 + col] = f2bf(acc[mf][n][r] + bb);
        }
    }
}

// ---------------------------------------------------------------------------
// Generic K=256 MFMA GEMM, BM=16: C[M][N] = A[M][256] @ Wt^T + bias
// 256 thr = 4 waves; wave w owns cols [w*NF*16, ...). grid = M/16.
// A dtype: f32 (cvt in-register) or bf16 (direct short8 load).
// ---------------------------------------------------------------------------
template<int NF, bool ABF16, bool OBF16>
__global__ __launch_bounds__(256) void gemm_k256(
    const void* __restrict__ Av, const unsigned short* __restrict__ Wt,
    const float* __restrict__ bias, void* __restrict__ Cv)
{
    const int wave = threadIdx.x >> 6;
    const int lane = threadIdx.x & 63;
    const int lhi = lane >> 4, llo = lane & 15;
    const int mBase = blockIdx.x * 16;
    const int colBase = wave * (NF * 16);
    const int N = NF * 64;

    f32x4 acc[NF];
#pragma unroll
    for (int n = 0; n < NF; ++n)
        acc[n] = (f32x4){0.f, 0.f, 0.f, 0.f};

#pragma unroll
    for (int ks = 0; ks < 8; ++ks) {
        const int kk = ks * 32 + lhi * 8;
        short8 a;
        if (ABF16) {
            a = *reinterpret_cast<const short8*>(
                (const unsigned short*)Av + (size_t)(mBase + llo) * 256 + kk);
        } else {
            const float* ap = (const float*)Av + (size_t)(mBase + llo) * 256 + kk;
            f32x4 f0 = *reinterpret_cast<const f32x4*>(ap);
            f32x4 f1 = *reinterpret_cast<const f32x4*>(ap + 4);
            short8 t;
            t[0] = (short)f2bf(f0[0]); t[1] = (short)f2bf(f0[1]);
            t[2] = (short)f2bf(f0[2]); t[3] = (short)f2bf(f0[3]);
            t[4] = (short)f2bf(f1[0]); t[5] = (short)f2bf(f1[1]);
            t[6] = (short)f2bf(f1[2]); t[7] = (short)f2bf(f1[3]);
            a = t;
        }
        short8 b[NF];
#pragma unroll
        for (int n = 0; n < NF; ++n) {
            const unsigned short* bp =
                Wt + (size_t)(colBase + n * 16 + llo) * 256 + kk;
            b[n] = *reinterpret_cast<const short8*>(bp);
        }
#pragma unroll
        for (int n = 0; n < NF; ++n)
            acc[n] = __builtin_amdgcn_mfma_f32_16x16x32_bf16(
                a, b[n], acc[n], 0, 0, 0);
    }

    const int row0 = mBase + lhi * 4;
#pragma unroll
    for (int n = 0; n < NF; ++n) {
        const int col = colBase + n * 16 + llo;
        const float bb = bias[col];
#pragma unroll
        for (int r = 0; r < 4; ++r) {
            float v = acc[n][r] + bb;
            size_t idx = (size_t)(row0 + r) * N + col;
            if (OBF16) ((unsigned short*)Cv)[idx] = f2bf(v);
            else       ((float*)Cv)[idx] = v;
        }
    }
}

// ---------------------------------------------------------------------------
// Sampling v3: block = one (b,q) [XCD-pinned batch], wave = one head.
// Wave = 4 groups x 16 lanes; group g = point p of each level; lane ld
// covers dims {2ld,2ld+1} via ushort2 loads. Softmax is sub-wave-parallel:
// sub-lane i=lane&15 owns logit i; shfl_xor(16) butterflies for max/sum,
// 4 shfl broadcasts for the per-level weights (1 exp/lane vs 16 before).
// Output written bf16.
// ---------------------------------------------------------------------------
__global__ __launch_bounds__(512) void ms_sample_kernel(
    const unsigned short* __restrict__ value,  // [8*21760][256] bf16
    const float* __restrict__ proj,            // [8000][384] f32
    const float* __restrict__ refp,            // [8][1000][4][2] f32
    unsigned short* __restrict__ out_h)        // [8000][256] bf16
{
    const int bid = blockIdx.x;
    const int b = bid & 7;                     // XCD-pinned batch
    const int q = bid >> 3;
    const int bq = b * LEN_Q + q;

    const int h = threadIdx.x >> 6;            // 0..7
    const int lane = threadIdx.x & 63;
    const int g = (lane >> 4) & 3;             // point index p
    const int ld = lane & 15;                  // dim pair: dims 2ld, 2ld+1

    const float* prow = proj + (size_t)bq * 384;

    // sub-wave-parallel softmax over this head's 16 logits
    float lg = prow[256 + h * 16 + ld];
    float mx = lg;
    mx = fmaxf(mx, __shfl_xor(mx, 1, 16));
    mx = fmaxf(mx, __shfl_xor(mx, 2, 16));
    mx = fmaxf(mx, __shfl_xor(mx, 4, 16));
    mx = fmaxf(mx, __shfl_xor(mx, 8, 16));
    float e = __expf(lg - mx);
    float den = e;
    den += __shfl_xor(den, 1, 16);
    den += __shfl_xor(den, 2, 16);
    den += __shfl_xor(den, 4, 16);
    den += __shfl_xor(den, 8, 16);
    const float w = e / den;                   // sub-lane i holds w_i
    float myw[4];
#pragma unroll
    for (int l = 0; l < 4; ++l)
        myw[l] = __shfl(w, l * 4 + g, 16);

    const unsigned short* vbase =
        value + (size_t)b * LEN_IN * 256 + h * 32 + 2 * ld;

    unsigned int vraw[4][4];
    float wgt[4][4];

    // phase 1: addresses + weights + all 16 loads (branchless)
#pragma unroll
    for (int l = 0; l < 4; ++l) {
        const int Wl = 128 >> l;               // Hl == Wl
        const int STL[4] = {0, 16384, 20480, 21504};
        const int st = STL[l];
        const int s = l * 4 + g;

        const float dx = prow[h * 32 + 2 * s];
        const float dy = prow[h * 32 + 2 * s + 1];
        const float rx = refp[((size_t)bq * 4 + l) * 2 + 0];
        const float ry = refp[((size_t)bq * 4 + l) * 2 + 1];

        const float x = rx * (float)Wl + dx - 0.5f;
        const float y = ry * (float)Wl + dy - 0.5f;
        const float x0f = floorf(x), y0f = floorf(y);
        const int x0 = (int)x0f, y0 = (int)y0f;
        const float wx1 = x - x0f, wy1 = y - y0f;
        const float wx0 = 1.f - wx1, wy0 = 1.f - wy1;
        const float ws = myw[l];

        const int x0c = min(max(x0, 0), Wl - 1);
        const int x1c = min(max(x0 + 1, 0), Wl - 1);
        const int y0c = min(max(y0, 0), Wl - 1);
        const int y1c = min(max(y0 + 1, 0), Wl - 1);
        const float fx0 = (x0 >= 0 && x0 < Wl) ? 1.f : 0.f;
        const float fx1 = (x0 + 1 >= 0 && x0 + 1 < Wl) ? 1.f : 0.f;
        const float fy0 = (y0 >= 0 && y0 < Wl) ? 1.f : 0.f;
        const float fy1 = (y0 + 1 >= 0 && y0 + 1 < Wl) ? 1.f : 0.f;

        const int r0 = st + y0c * Wl, r1 = st + y1c * Wl;
        vraw[l][0] = *reinterpret_cast<const unsigned int*>(vbase + (size_t)(r0 + x0c) * 256);
        vraw[l][1] = *reinterpret_cast<const unsigned int*>(vbase + (size_t)(r0 + x1c) * 256);
        vraw[l][2] = *reinterpret_cast<const unsigned int*>(vbase + (size_t)(r1 + x0c) * 256);
        vraw[l][3] = *reinterpret_cast<const unsigned int*>(vbase + (size_t)(r1 + x1c) * 256);
        wgt[l][0] = ws * wy0 * wx0 * fy0 * fx0;
        wgt[l][1] = ws * wy0 * wx1 * fy0 * fx1;
        wgt[l][2] = ws * wy1 * wx0 * fy1 * fx0;
        wgt[l][3] = ws * wy1 * wx1 * fy1 * fx1;
    }

    // phase 2: weighted accumulate (bf16 lo/hi -> f32)
    float ax = 0.f, ay = 0.f;
#pragma unroll
    for (int l = 0; l < 4; ++l)
#pragma unroll
        for (int n = 0; n < 4; ++n) {
            const unsigned int v = vraw[l][n];
            const float wv = wgt[l][n];
            ax += wv * bf2f((unsigned short)(v & 0xFFFFu));
            ay += wv * bf2f((unsigned short)(v >> 16));
        }

    // reduce across the 4 groups (lanes ^16, ^32)
    ax += __shfl_xor(ax, 16, 64);
    ay += __shfl_xor(ay, 16, 64);
    ax += __shfl_xor(ax, 32, 64);
    ay += __shfl_xor(ay, 32, 64);

    if (g == 0) {
        unsigned int o = (unsigned int)f2bf(ax) | ((unsigned int)f2bf(ay) << 16);
        *reinterpret_cast<unsigned int*>(
            out_h + (size_t)bq * 256 + h * 32 + 2 * ld) = o;
    }
}

// ---------------------------------------------------------------------------
extern "C" void kernel_launch(void* const* d_in, const int* in_sizes, int n_in,
                              void* d_out, int out_size, void* d_ws, size_t ws_size,
                              hipStream_t stream)
{
    const float* query  = (const float*)d_in[0];
    const float* refp   = (const float*)d_in[1];
    const float* inpf   = (const float*)d_in[2];
    const float* W_off  = (const float*)d_in[5];
    const float* b_off  = (const float*)d_in[6];
    const float* W_attn = (const float*)d_in[7];
    const float* b_attn = (const float*)d_in[8];
    const float* W_val  = (const float*)d_in[9];
    const float* b_val  = (const float*)d_in[10];
    const float* W_out  = (const float*)d_in[11];
    const float* b_out  = (const float*)d_in[12];

    char* ws = (char*)d_ws;
    unsigned short* value = (unsigned short*)(ws);                    // 89,128,960 B
    float*          proj  = (float*)(ws + 89128960);                  // 12,288,000 B
    unsigned short* out_h = (unsigned short*)(ws + 89128960 + 12288000); // 4,096,000 B
    unsigned short* WtVp  = (unsigned short*)(ws + 109608960);        //    131,072 B
    unsigned short* WtC   = (unsigned short*)(ws + 109740032);        //    196,608 B
    unsigned short* WtO   = (unsigned short*)(ws + 109936640);        //    131,072 B
    float*          bcat  = (float*)(ws + 110067712);                 //      1,536 B

    prep_kernel<<<898, 256, 0, stream>>>(W_val, W_off, W_attn, W_out,
                                         b_off, b_attn, WtVp, WtC, WtO, bcat);

    // value = input_flatten @ W_val + b_val   -> bf16 [174080][256]
    gemm_value<<<(N_BATCH * LEN_IN) / 64, 256, 0, stream>>>(
        inpf, WtVp, b_val, value);

    // proj = query @ [W_off|W_attn] + bias -> f32 [8000][384]
    gemm_k256<6, false, false><<<(N_BATCH * LEN_Q) / 16, 256, 0, stream>>>(
        query, WtC, bcat, (void*)proj);

    // bilinear sampling + softmax-weighted sum -> out_h bf16 [8000][256]
    ms_sample_kernel<<<N_BATCH * LEN_Q, 512, 0, stream>>>(
        value, proj, refp, out_h);

    // out = out_h @ W_out + b_out -> d_out f32 [8000][256]
    gemm_k256<4, true, false><<<(N_BATCH * LEN_Q) / 16, 256, 0, stream>>>(
        out_h, WtO, b_out, d_out);
}

// Round 6
// 132.165 us; speedup vs baseline: 2.9075x; 1.0352x over previous
//
#include <hip/hip_runtime.h>
#include <hip/hip_bf16.h>

#define D_MODEL 256
#define N_HEADS 8
#define D_HEAD 32
#define N_LEVELS 4
#define N_POINTS 4
#define LEN_IN 21760
#define N_BATCH 8
#define LEN_Q 1000

typedef __attribute__((ext_vector_type(8))) short short8;
typedef __attribute__((ext_vector_type(4))) float f32x4;
typedef __attribute__((ext_vector_type(4))) unsigned int u32x4;

typedef const __attribute__((address_space(1))) void* gp1;
typedef __attribute__((address_space(3))) void* lp3;

__device__ __forceinline__ unsigned short f2bf(float f) {
    unsigned int u = __float_as_uint(f);
    u += 0x7FFFu + ((u >> 16) & 1u);   // RNE
    return (unsigned short)(u >> 16);
}
__device__ __forceinline__ float bf2f(unsigned short s) {
    return __uint_as_float(((unsigned int)s) << 16);
}

// ---------------------------------------------------------------------------
// prep:
//   WtVp [8][16][64][8] bf16  <- W_val^T packed MFMA-fragment-major
//   WtC  [384][256] bf16      <- [W_off | W_attn]^T row-major
//   WtO  [256][256] bf16      <- W_out^T row-major
//   bcat [384] f32            <- [b_off | b_attn]
// ---------------------------------------------------------------------------
__global__ __launch_bounds__(256) void prep_kernel(
    const float* __restrict__ Wv, const float* __restrict__ Wo,
    const float* __restrict__ Wa, const float* __restrict__ Wu,
    const float* __restrict__ boff, const float* __restrict__ battn,
    unsigned short* __restrict__ WtVp, unsigned short* __restrict__ WtC,
    unsigned short* __restrict__ WtO, float* __restrict__ bcat)
{
    int idx = blockIdx.x * 256 + threadIdx.x;
    if (idx < 65536) {
        int j = idx & 7, lane = (idx >> 3) & 63, nf = (idx >> 9) & 15, ks = idx >> 13;
        int col = nf * 16 + (lane & 15);
        int k = ks * 32 + (lane >> 4) * 8 + j;
        WtVp[idx] = f2bf(Wv[k * 256 + col]);
    } else if (idx < 65536 + 98304) {
        int j = idx - 65536;
        int n = j >> 8, k = j & 255;
        float s = (n < 256) ? Wo[k * 256 + n] : Wa[k * 128 + (n - 256)];
        WtC[j] = f2bf(s);
    } else if (idx < 65536 + 98304 + 65536) {
        int j = idx - (65536 + 98304);
        int n = j >> 8, k = j & 255;
        WtO[j] = f2bf(Wu[k * 256 + n]);
    } else if (idx < 65536 + 98304 + 65536 + 384) {
        int j = idx - (65536 + 98304 + 65536);
        bcat[j] = (j < 256) ? boff[j] : battn[j - 256];
    }
}

// ---------------------------------------------------------------------------
// Value GEMM: C_bf16[174080][256] = A_f32[174080][256] @ W_val + bias
// (unchanged — staged global_load_lds, double-buffered, swizzled)
// ---------------------------------------------------------------------------
__global__ __launch_bounds__(256) void gemm_value(
    const float* __restrict__ A,
    const unsigned short* __restrict__ Bp,   // [8][16][64][8] bf16
    const float* __restrict__ bias,
    unsigned short* __restrict__ C)
{
    __shared__ float lds[2][2048];           // 2 x 8KB (BM=64 rows x 128B)

    const int tid = threadIdx.x;
    const int wave = tid >> 6, lane = tid & 63;
    const int lhi = lane >> 4, llo = lane & 15;
    const int mBase = blockIdx.x * 64;

    const int soff = tid * 16;
    const int r0 = soff >> 7, cb0 = soff & 127;
    const size_t g0 = (size_t)r0 * 1024 + (size_t)(cb0 ^ ((r0 & 7) << 4));
    const size_t g1 = g0 + (size_t)32 * 1024;

    const char* Ab = (const char*)(A + (size_t)mBase * 256);
    const int dsto = soff >> 2;

    f32x4 acc[4][4];
#pragma unroll
    for (int mf = 0; mf < 4; ++mf)
#pragma unroll
        for (int n = 0; n < 4; ++n)
            acc[mf][n] = (f32x4){0.f, 0.f, 0.f, 0.f};

    {
        float* dst0 = &lds[0][dsto];
        __builtin_amdgcn_global_load_lds((gp1)(const void*)(Ab + g0),
                                         (lp3)dst0, 16, 0, 0);
        __builtin_amdgcn_global_load_lds((gp1)(const void*)(Ab + g1),
                                         (lp3)(dst0 + 1024), 16, 0, 0);
    }

#pragma unroll
    for (int kt = 0; kt < 8; ++kt) {
        const int cur = kt & 1;

        short8 b[4];
#pragma unroll
        for (int n = 0; n < 4; ++n)
            b[n] = *reinterpret_cast<const short8*>(
                Bp + ((size_t)(kt * 16 + wave * 4 + n) * 64 + lane) * 8);

        if (kt < 7) {
            const size_t off = (size_t)(kt + 1) * 128;
            float* dst0 = &lds[cur ^ 1][dsto];
            __builtin_amdgcn_global_load_lds((gp1)(const void*)(Ab + off + g0),
                                             (lp3)dst0, 16, 0, 0);
            __builtin_amdgcn_global_load_lds((gp1)(const void*)(Ab + off + g1),
                                             (lp3)(dst0 + 1024), 16, 0, 0);
        }

        __builtin_amdgcn_sched_barrier(0);
        if (kt < 7) asm volatile("s_waitcnt vmcnt(2)" ::: "memory");
        else        asm volatile("s_waitcnt vmcnt(0)" ::: "memory");
        __builtin_amdgcn_sched_barrier(0);
        __builtin_amdgcn_s_barrier();
        __builtin_amdgcn_sched_barrier(0);

        short8 af[4];
#pragma unroll
        for (int mf = 0; mf < 4; ++mf) {
            const int row = mf * 16 + llo;
            const int sz = (llo & 7) << 4;
            const char* base = (const char*)&lds[cur][0] + row * 128;
            f32x4 flo = *reinterpret_cast<const f32x4*>(base + ((lhi * 32) ^ sz));
            f32x4 fhi = *reinterpret_cast<const f32x4*>(base + ((lhi * 32 + 16) ^ sz));
            short8 t;
            t[0] = (short)f2bf(flo[0]); t[1] = (short)f2bf(flo[1]);
            t[2] = (short)f2bf(flo[2]); t[3] = (short)f2bf(flo[3]);
            t[4] = (short)f2bf(fhi[0]); t[5] = (short)f2bf(fhi[1]);
            t[6] = (short)f2bf(fhi[2]); t[7] = (short)f2bf(fhi[3]);
            af[mf] = t;
        }

#pragma unroll
        for (int mf = 0; mf < 4; ++mf)
#pragma unroll
            for (int n = 0; n < 4; ++n)
                acc[mf][n] = __builtin_amdgcn_mfma_f32_16x16x32_bf16(
                    af[mf], b[n], acc[mf][n], 0, 0, 0);

        __builtin_amdgcn_sched_barrier(0);
        __builtin_amdgcn_s_barrier();
        __builtin_amdgcn_sched_barrier(0);
    }

#pragma unroll
    for (int mf = 0; mf < 4; ++mf) {
        const int row0 = mBase + mf * 16 + lhi * 4;
#pragma unroll
        for (int n = 0; n < 4; ++n) {
            const int col = wave * 64 + n * 16 + llo;
            const float bb = bias[col];
#pragma unroll
            for (int r = 0; r < 4; ++r)
                C[(size_t)(row0 + r) * 256 + col] = f2bf(acc[mf][n][r] + bb);
        }
    }
}

// ---------------------------------------------------------------------------
// Generic K=256 MFMA GEMM, BM=16: C[M][N] = A[M][256] @ Wt^T + bias
// ---------------------------------------------------------------------------
template<int NF, bool ABF16, bool OBF16>
__global__ __launch_bounds__(256) void gemm_k256(
    const void* __restrict__ Av, const unsigned short* __restrict__ Wt,
    const float* __restrict__ bias, void* __restrict__ Cv)
{
    const int wave = threadIdx.x >> 6;
    const int lane = threadIdx.x & 63;
    const int lhi = lane >> 4, llo = lane & 15;
    const int mBase = blockIdx.x * 16;
    const int colBase = wave * (NF * 16);
    const int N = NF * 64;

    f32x4 acc[NF];
#pragma unroll
    for (int n = 0; n < NF; ++n)
        acc[n] = (f32x4){0.f, 0.f, 0.f, 0.f};

#pragma unroll
    for (int ks = 0; ks < 8; ++ks) {
        const int kk = ks * 32 + lhi * 8;
        short8 a;
        if (ABF16) {
            a = *reinterpret_cast<const short8*>(
                (const unsigned short*)Av + (size_t)(mBase + llo) * 256 + kk);
        } else {
            const float* ap = (const float*)Av + (size_t)(mBase + llo) * 256 + kk;
            f32x4 f0 = *reinterpret_cast<const f32x4*>(ap);
            f32x4 f1 = *reinterpret_cast<const f32x4*>(ap + 4);
            short8 t;
            t[0] = (short)f2bf(f0[0]); t[1] = (short)f2bf(f0[1]);
            t[2] = (short)f2bf(f0[2]); t[3] = (short)f2bf(f0[3]);
            t[4] = (short)f2bf(f1[0]); t[5] = (short)f2bf(f1[1]);
            t[6] = (short)f2bf(f1[2]); t[7] = (short)f2bf(f1[3]);
            a = t;
        }
        short8 b[NF];
#pragma unroll
        for (int n = 0; n < NF; ++n) {
            const unsigned short* bp =
                Wt + (size_t)(colBase + n * 16 + llo) * 256 + kk;
            b[n] = *reinterpret_cast<const short8*>(bp);
        }
#pragma unroll
        for (int n = 0; n < NF; ++n)
            acc[n] = __builtin_amdgcn_mfma_f32_16x16x32_bf16(
                a, b[n], acc[n], 0, 0, 0);
    }

    const int row0 = mBase + lhi * 4;
#pragma unroll
    for (int n = 0; n < NF; ++n) {
        const int col = colBase + n * 16 + llo;
        const float bb = bias[col];
#pragma unroll
        for (int r = 0; r < 4; ++r) {
            float v = acc[n][r] + bb;
            size_t idx = (size_t)(row0 + r) * N + col;
            if (OBF16) ((unsigned short*)Cv)[idx] = f2bf(v);
            else       ((float*)Cv)[idx] = v;
        }
    }
}

// ---------------------------------------------------------------------------
// Sampling v4 (task-per-lane): block = one (b,q), wave = one head.
// lane -> task = lane>>2 in [0,16) = (level l = task>>2, point p = task&3);
//         qd   = lane&3 covers dims [8*qd, 8*qd+8).
// Each lane computes ONE sample's address math (serial chain 4x shorter than
// v3), then 4 x dwordx4 neighbor loads (16B/lane; a 4-lane group covers the
// full 64B head-row segment). Accumulate 8 dims/lane, 4-step shfl_xor
// reduction over the 16 tasks, lanes 0..3 write 16B bf16 stores.
// ---------------------------------------------------------------------------
__global__ __launch_bounds__(512) void ms_sample_kernel(
    const unsigned short* __restrict__ value,  // [8*21760][256] bf16
    const float* __restrict__ proj,            // [8000][384] f32
    const float* __restrict__ refp,            // [8][1000][4][2] f32
    unsigned short* __restrict__ out_h)        // [8000][256] bf16
{
    const int bid = blockIdx.x;
    const int b = bid & 7;                     // XCD-pinned batch
    const int q = bid >> 3;
    const int bq = b * LEN_Q + q;

    const int h = threadIdx.x >> 6;            // 0..7
    const int lane = threadIdx.x & 63;
    const int task = lane >> 2;                // 0..15 = l*4+p
    const int l = task >> 2;
    const int qd = lane & 3;                   // dim quarter

    const float* prow = proj + (size_t)bq * 384;

    // softmax over this head's 16 logits (each 16-lane group redundantly)
    float lg = prow[256 + h * 16 + (lane & 15)];
    float mx = lg;
    mx = fmaxf(mx, __shfl_xor(mx, 1, 16));
    mx = fmaxf(mx, __shfl_xor(mx, 2, 16));
    mx = fmaxf(mx, __shfl_xor(mx, 4, 16));
    mx = fmaxf(mx, __shfl_xor(mx, 8, 16));
    float e = __expf(lg - mx);
    float den = e;
    den += __shfl_xor(den, 1, 16);
    den += __shfl_xor(den, 2, 16);
    den += __shfl_xor(den, 4, 16);
    den += __shfl_xor(den, 8, 16);
    const float wsm = e / den;                 // sub-lane i holds w_i
    const float ws = __shfl(wsm, task, 16);    // this lane's task weight

    // this lane's sample math (one sample per lane)
    const int Wl = 128 >> l;                   // Hl == Wl
    const int st = (65536 - (65536 >> (l << 1))) / 3;  // level start row

    const float dx = prow[h * 32 + 2 * task];
    const float dy = prow[h * 32 + 2 * task + 1];
    const float rx = refp[((size_t)bq * 4 + l) * 2 + 0];
    const float ry = refp[((size_t)bq * 4 + l) * 2 + 1];

    const float Wlf = (float)Wl;
    const float x = rx * Wlf + dx - 0.5f;
    const float y = ry * Wlf + dy - 0.5f;
    const float x0f = floorf(x), y0f = floorf(y);
    const int x0 = (int)x0f, y0 = (int)y0f;
    const float wx1 = x - x0f, wy1 = y - y0f;
    const float wx0 = 1.f - wx1, wy0 = 1.f - wy1;

    const int x0c = min(max(x0, 0), Wl - 1);
    const int x1c = min(max(x0 + 1, 0), Wl - 1);
    const int y0c = min(max(y0, 0), Wl - 1);
    const int y1c = min(max(y0 + 1, 0), Wl - 1);
    const float fx0 = (x0 >= 0 && x0 < Wl) ? 1.f : 0.f;
    const float fx1 = (x0 + 1 >= 0 && x0 + 1 < Wl) ? 1.f : 0.f;
    const float fy0 = (y0 >= 0 && y0 < Wl) ? 1.f : 0.f;
    const float fy1 = (y0 + 1 >= 0 && y0 + 1 < Wl) ? 1.f : 0.f;

    const int rr0 = st + y0c * Wl, rr1 = st + y1c * Wl;
    const int r00 = rr0 + x0c, r01 = rr0 + x1c;
    const int r10 = rr1 + x0c, r11 = rr1 + x1c;

    float wgt[4];
    wgt[0] = ws * wy0 * wx0 * fy0 * fx0;
    wgt[1] = ws * wy0 * wx1 * fy0 * fx1;
    wgt[2] = ws * wy1 * wx0 * fy1 * fx0;
    wgt[3] = ws * wy1 * wx1 * fy1 * fx1;

    // 4 x 16B neighbor loads (this lane's dim quarter)
    const char* vb = (const char*)value + (size_t)b * LEN_IN * 512
                   + h * 64 + qd * 16;
    u32x4 v0 = *reinterpret_cast<const u32x4*>(vb + (size_t)r00 * 512);
    u32x4 v1 = *reinterpret_cast<const u32x4*>(vb + (size_t)r01 * 512);
    u32x4 v2 = *reinterpret_cast<const u32x4*>(vb + (size_t)r10 * 512);
    u32x4 v3 = *reinterpret_cast<const u32x4*>(vb + (size_t)r11 * 512);

    // weighted accumulate: 8 dims per lane
    float acc[8];
#pragma unroll
    for (int j = 0; j < 8; ++j) acc[j] = 0.f;
#pragma unroll
    for (int n = 0; n < 4; ++n) {
        const u32x4 v = (n == 0) ? v0 : (n == 1) ? v1 : (n == 2) ? v2 : v3;
        const float wn = wgt[n];
#pragma unroll
        for (int j = 0; j < 4; ++j) {
            const unsigned int u = v[j];
            acc[2 * j]     += wn * bf2f((unsigned short)(u & 0xFFFFu));
            acc[2 * j + 1] += wn * bf2f((unsigned short)(u >> 16));
        }
    }

    // reduce over the 16 tasks (stride-4 lane sets)
#pragma unroll
    for (int j = 0; j < 8; ++j) {
        acc[j] += __shfl_xor(acc[j], 4, 64);
        acc[j] += __shfl_xor(acc[j], 8, 64);
        acc[j] += __shfl_xor(acc[j], 16, 64);
        acc[j] += __shfl_xor(acc[j], 32, 64);
    }

    if (task == 0) {
        u32x4 o;
#pragma unroll
        for (int j = 0; j < 4; ++j)
            o[j] = (unsigned int)f2bf(acc[2 * j]) |
                   ((unsigned int)f2bf(acc[2 * j + 1]) << 16);
        *reinterpret_cast<u32x4*>(
            out_h + (size_t)bq * 256 + h * 32 + qd * 8) = o;
    }
}

// ---------------------------------------------------------------------------
extern "C" void kernel_launch(void* const* d_in, const int* in_sizes, int n_in,
                              void* d_out, int out_size, void* d_ws, size_t ws_size,
                              hipStream_t stream)
{
    const float* query  = (const float*)d_in[0];
    const float* refp   = (const float*)d_in[1];
    const float* inpf   = (const float*)d_in[2];
    const float* W_off  = (const float*)d_in[5];
    const float* b_off  = (const float*)d_in[6];
    const float* W_attn = (const float*)d_in[7];
    const float* b_attn = (const float*)d_in[8];
    const float* W_val  = (const float*)d_in[9];
    const float* b_val  = (const float*)d_in[10];
    const float* W_out  = (const float*)d_in[11];
    const float* b_out  = (const float*)d_in[12];

    char* ws = (char*)d_ws;
    unsigned short* value = (unsigned short*)(ws);                    // 89,128,960 B
    float*          proj  = (float*)(ws + 89128960);                  // 12,288,000 B
    unsigned short* out_h = (unsigned short*)(ws + 89128960 + 12288000); // 4,096,000 B
    unsigned short* WtVp  = (unsigned short*)(ws + 109608960);        //    131,072 B
    unsigned short* WtC   = (unsigned short*)(ws + 109740032);        //    196,608 B
    unsigned short* WtO   = (unsigned short*)(ws + 109936640);        //    131,072 B
    float*          bcat  = (float*)(ws + 110067712);                 //      1,536 B

    prep_kernel<<<898, 256, 0, stream>>>(W_val, W_off, W_attn, W_out,
                                         b_off, b_attn, WtVp, WtC, WtO, bcat);

    // value = input_flatten @ W_val + b_val   -> bf16 [174080][256]
    gemm_value<<<(N_BATCH * LEN_IN) / 64, 256, 0, stream>>>(
        inpf, WtVp, b_val, value);

    // proj = query @ [W_off|W_attn] + bias -> f32 [8000][384]
    gemm_k256<6, false, false><<<(N_BATCH * LEN_Q) / 16, 256, 0, stream>>>(
        query, WtC, bcat, (void*)proj);

    // bilinear sampling + softmax-weighted sum -> out_h bf16 [8000][256]
    ms_sample_kernel<<<N_BATCH * LEN_Q, 512, 0, stream>>>(
        value, proj, refp, out_h);

    // out = out_h @ W_out + b_out -> d_out f32 [8000][256]
    gemm_k256<4, true, false><<<(N_BATCH * LEN_Q) / 16, 256, 0, stream>>>(
        out_h, WtO, b_out, d_out);
}